// Round 7
// baseline (175.787 us; speedup 1.0000x reference)
//
#include <hip/hip_runtime.h>

#define NROWS 4096
#define DIM   128
#define KCLS  4
#define NTILE 64                 // 64x64 anchor tiles
#define NTRI  2080               // NTILE*(NTILE+1)/2 triangular blocks
#define MARGIN_F 0.02f
#define EPS_F    1e-12f

typedef unsigned short ushort_t;
typedef unsigned int   uint_t;
typedef __attribute__((ext_vector_type(8)))  short bf16x8;
typedef __attribute__((ext_vector_type(16))) float f32x16;

__device__ __forceinline__ ushort_t rne_bf16(float v, float& back) {
    uint_t u = __float_as_uint(v);
    uint_t r = (u + 0x7fffu + ((u >> 16) & 1u)) >> 16;
    back = __uint_as_float(r << 16);
    return (ushort_t)r;
}

// ---------------- kernel 1: norms, pos distances, bf16 hi/lo split ----------
__global__ void k_prep(const float* __restrict__ x,
                       float* __restrict__ sqn,
                       float4* __restrict__ posd4,
                       ushort_t* __restrict__ xh,
                       ushort_t* __restrict__ xl,
                       uint_t* __restrict__ imask,
                       uint_t* __restrict__ jmask,
                       float* __restrict__ posp)
{
    if (blockIdx.x == 0) {
        const int tt = threadIdx.x;
        if (tt < 128) imask[tt] = 0u; else jmask[tt - 128] = 0u;
    }
    const int wave = threadIdx.x >> 6;
    const int lane = threadIdx.x & 63;
    const int a = (blockIdx.x << 2) + wave;

    const float2 va = ((const float2*)(x + (size_t)a * DIM))[lane];

    float hb0, hb1;
    const ushort_t h0 = rne_bf16(va.x, hb0);
    const ushort_t h1 = rne_bf16(va.y, hb1);
    float dummy;
    const ushort_t l0 = rne_bf16(va.x - hb0, dummy);
    const ushort_t l1 = rne_bf16(va.y - hb1, dummy);
    ((uint_t*)xh)[a * 64 + lane] = (uint_t)h0 | ((uint_t)h1 << 16);
    ((uint_t*)xl)[a * 64 + lane] = (uint_t)l0 | ((uint_t)l1 << 16);

    float s = va.x * va.x + va.y * va.y;
#pragma unroll
    for (int off = 32; off; off >>= 1) s += __shfl_xor(s, off);
    if (lane == 0) sqn[a] = s;

    const int cs = a & ~(KCLS - 1), pic = a & (KCLS - 1);
    float pd[3];
#pragma unroll
    for (int o = 0; o < KCLS - 1; ++o) {
        const int p = cs + o + (o >= pic ? 1 : 0);
        const float2 vp = ((const float2*)(x + (size_t)p * DIM))[lane];
        float dp = va.x * vp.x + va.y * vp.y;
        float sp = vp.x * vp.x + vp.y * vp.y;
#pragma unroll
        for (int off = 32; off; off >>= 1) {
            dp += __shfl_xor(dp, off);
            sp += __shfl_xor(sp, off);
        }
        pd[o] = sqrtf(fmaxf(s + sp - 2.f * dp, EPS_F));
    }
    __shared__ float pblk[4];
    if (lane == 0) {
        posd4[a] = make_float4(pd[0], pd[1], pd[2], 0.f);
        pblk[wave] = pd[0] + pd[1] + pd[2];
    }
    __syncthreads();
    if (threadIdx.x == 0)
        posp[blockIdx.x] = pblk[0] + pblk[1] + pblk[2] + pblk[3];
}

// ---------------- kernel 2: no-LDS MFMA Gram + fused hinge ----------------
// Data is L2-resident (2 MB); MFMA fragments are contiguous 16B row chunks,
// loaded straight from global. No LDS staging, no barriers, no vmcnt drains.
__global__ __launch_bounds__(256, 4) void k_tiles(
    const ushort_t* __restrict__ xh, const ushort_t* __restrict__ xl,
    const float* __restrict__ sqn, const float4* __restrict__ posd4,
    uint_t* __restrict__ imask, uint_t* __restrict__ jmask,
    float4* __restrict__ partial)
{
    // triangular decode: bid -> (ti, tj), tj >= ti
    const int bidp = (NTRI - 1) - (int)blockIdx.x;
    int m = (int)((sqrtf((float)(8 * bidp + 1)) - 1.0f) * 0.5f);
    while ((m + 1) * (m + 2) / 2 <= bidp) ++m;
    while (m * (m + 1) / 2 > bidp) --m;
    const int ti = (NTILE - 1) - m;
    const int tj = (NTILE - 1) - (bidp - m * (m + 1) / 2);

    const int t    = threadIdx.x;
    const int wave = t >> 6, lane = t & 63;
    const int wr = wave >> 1, wc = wave & 1;
    const int col = lane & 31, hi = lane >> 5;
    const int ibase = ti << 6, jbase = tj << 6;
    const bool diag = (ti == tj);

    f32x16 acc;
#pragma unroll
    for (int r = 0; r < 16; ++r) acc[r] = 0.f;

    // per-lane fragment base: row (lane&31) of the wave's 32-row band,
    // k-offset (lane>>5)*8   (32x32x16 bf16 A/B fragment layout)
    const size_t abase = (size_t)(ibase + (wr << 5) + col) * DIM + (hi << 3);
    const size_t bbase = (size_t)(jbase + (wc << 5) + col) * DIM + (hi << 3);
    const ushort_t* pah = xh + abase;
    const ushort_t* pal = xl + abase;
    const ushort_t* pbh = xh + bbase;
    const ushort_t* pbl = xl + bbase;

#pragma unroll
    for (int kk = 0; kk < 8; ++kk) {
        const int ko = kk << 4;
        const bf16x8 ah = *(const bf16x8*)(pah + ko);
        const bf16x8 al = *(const bf16x8*)(pal + ko);
        const bf16x8 bh = *(const bf16x8*)(pbh + ko);
        const bf16x8 bl = *(const bf16x8*)(pbl + ko);
        acc = __builtin_amdgcn_mfma_f32_32x32x16_bf16(ah, bh, acc, 0, 0, 0);
        acc = __builtin_amdgcn_mfma_f32_32x32x16_bf16(ah, bl, acc, 0, 0, 0);
        acc = __builtin_amdgcn_mfma_f32_32x32x16_bf16(al, bh, acc, 0, 0, 0);
    }

    // ---------------- epilogue ----------------
    const int jg = jbase + (wc << 5) + col;
    const float sqj = sqn[jg];
    const float4 pj = posd4[jg];
    const float sqi_l = sqn[ibase + (wr << 5) + col];
    const float4 pi_l = posd4[ibase + (wr << 5) + col];

    float ts = 0.f, ns = 0.f, cntf = 0.f;
    uint_t iam = 0, jany = 0;

    const int jcls = jg >> 2;
#pragma unroll
    for (int r = 0; r < 16; ++r) {
        const int rbase = (r & 3) + ((r >> 2) << 3);        // C/D row map
        const int src = rbase + (hi << 2);
        const float sqi = __shfl(sqi_l, src);
        const float p0  = __shfl(pi_l.x, src);
        const float p1  = __shfl(pi_l.y, src);
        const float p2  = __shfl(pi_l.z, src);
        const int i = ibase + (wr << 5) + src;
        const bool skip = diag && ((i >> 2) == jcls);
        const float dd = sqrtf(fmaxf(sqi + sqj - 2.f * acc[r], EPS_F));
        if (!skip) {
            ns += dd;                                       // anchor i
            const float t0 = p0 + MARGIN_F - dd;
            const float t1 = p1 + MARGIN_F - dd;
            const float t2 = p2 + MARGIN_F - dd;
            uint_t v = 0;
            if (t0 > 0.f) { ts += t0; cntf += 1.f; v = 1u; }
            if (t1 > 0.f) { ts += t1; cntf += 1.f; v = 1u; }
            if (t2 > 0.f) { ts += t2; cntf += 1.f; v = 1u; }
            iam |= v << r;
            if (!diag) {                                    // anchor j
                ns += dd;
                const float u0 = pj.x + MARGIN_F - dd;
                const float u1 = pj.y + MARGIN_F - dd;
                const float u2 = pj.z + MARGIN_F - dd;
                if (u0 > 0.f) { ts += u0; cntf += 1.f; jany = 1u; }
                if (u1 > 0.f) { ts += u1; cntf += 1.f; jany = 1u; }
                if (u2 > 0.f) { ts += u2; cntf += 1.f; jany = 1u; }
            }
        }
    }

    // i-flags: OR-reduce per 32-lane half, remap reg-bits -> row-bits
    uint_t iam_all = iam;
#pragma unroll
    for (int off = 1; off < 32; off <<= 1) iam_all |= __shfl_xor(iam_all, off);
    uint_t rowmask = 0;
#pragma unroll
    for (int r = 0; r < 16; ++r)
        if ((iam_all >> r) & 1u)
            rowmask |= 1u << ((r & 3) + ((r >> 2) << 3) + (hi << 2));
    if ((lane == 0 || lane == 32) && rowmask)
        atomicOr(&imask[(ti << 1) + wr], rowmask);

    // j-flags: one ballot -> column mask -> one atomicOr per wave
    const unsigned long long bm = __ballot(jany != 0);
    const uint_t jm = (uint_t)bm | (uint_t)(bm >> 32);
    if (lane == 0 && jm) atomicOr(&jmask[(tj << 1) + wc], jm);

    // scalar partials: wave shfl reduce, then block reduce via tiny LDS
#pragma unroll
    for (int off = 32; off; off >>= 1) {
        ts   += __shfl_down(ts, off);
        ns   += __shfl_down(ns, off);
        cntf += __shfl_down(cntf, off);
    }
    __shared__ float4 wpart[4];
    if (lane == 0) wpart[wave] = make_float4(ts, ns, cntf, 0.f);
    __syncthreads();
    if (t == 0) {
        float4 s = wpart[0];
        s.x += wpart[1].x + wpart[2].x + wpart[3].x;
        s.y += wpart[1].y + wpart[2].y + wpart[3].y;
        s.z += wpart[1].z + wpart[2].z + wpart[3].z;
        partial[blockIdx.x] = s;
    }
}

// ---------------- kernel 3: finalize (1024 threads) ----------------
__global__ void k_final(const uint_t* __restrict__ imask,
                        const uint_t* __restrict__ jmask,
                        const float4* __restrict__ partial,
                        const float* __restrict__ posp,
                        float* __restrict__ out)
{
    const int t = threadIdx.x;      // 1024
    const int lane = t & 63, wave = t >> 6;
    double ts = 0.0, ns = 0.0, cnt = 0.0, ps = 0.0;
    uint_t zc = 0;

    for (int idx = t; idx < NTRI; idx += 1024) {
        const float4 p = partial[idx];
        ts += (double)p.x; ns += (double)p.y; cnt += (double)p.z;
    }
    if (t < 1024) ps = (double)posp[t];
    if (t < 128) zc = 32u - (uint_t)__popc(imask[t] | jmask[t]);

#pragma unroll
    for (int off = 32; off; off >>= 1) {
        ts  += __shfl_down(ts, off);
        ns  += __shfl_down(ns, off);
        cnt += __shfl_down(cnt, off);
        ps  += __shfl_down(ps, off);
        zc  += __shfl_down(zc, off);
    }
    __shared__ double s0[16], s1[16], s2[16], s3[16];
    __shared__ uint_t s4[16];
    if (lane == 0) { s0[wave] = ts; s1[wave] = ns; s2[wave] = cnt; s3[wave] = ps; s4[wave] = zc; }
    __syncthreads();
    if (t == 0) {
        double a0 = 0, a1 = 0, a2 = 0, a3 = 0; uint_t a4 = 0;
#pragma unroll
        for (int w = 0; w < 16; ++w) {
            a0 += s0[w]; a1 += s1[w]; a2 += s2[w]; a3 += s3[w]; a4 += s4[w];
        }
        out[0] = (float)(a2 > 0.0 ? a0 / a2 : 0.0);
        out[1] = (float)((double)a4 / (double)NROWS);
        out[2] = (float)(a3 / ((double)NROWS * 3.0));
        out[3] = (float)(a1 / ((double)NROWS * (double)(NROWS - KCLS)));
    }
}

extern "C" void kernel_launch(void* const* d_in, const int* in_sizes, int n_in,
                              void* d_out, int out_size, void* d_ws, size_t ws_size,
                              hipStream_t stream)
{
    const float* x = (const float*)d_in[0];
    float* out = (float*)d_out;
    char* ws = (char*)d_ws;

    // workspace layout:
    // imask 512B | jmask 512B | sqn 16K | posd4 64K | partial 2080*16 |
    // posp 4K | xh 1M | xl 1M
    uint_t* imask   = (uint_t*)ws;
    uint_t* jmask   = (uint_t*)(ws + 512);
    float*  sqn     = (float*)(ws + 1024);
    float4* posd4   = (float4*)(ws + 1024 + 16384);
    float4* partial = (float4*)(ws + 1024 + 16384 + 65536);
    float*  posp    = (float*)(ws + 1024 + 16384 + 65536 + 33280);
    ushort_t* xh    = (ushort_t*)(ws + 1024 + 16384 + 65536 + 33280 + 4096);
    ushort_t* xl    = (ushort_t*)(ws + 1024 + 16384 + 65536 + 33280 + 4096 + 1048576);

    k_prep<<<NROWS / 4, 256, 0, stream>>>(x, sqn, posd4, xh, xl, imask, jmask, posp);
    k_tiles<<<NTRI, 256, 0, stream>>>(xh, xl, sqn, posd4, imask, jmask, partial);
    k_final<<<1, 1024, 0, stream>>>(imask, jmask, partial, posp, out);
}